// Round 12
// baseline (92.791 us; speedup 1.0000x reference)
//
#include <hip/hip_runtime.h>
#include <hip/hip_bf16.h>

typedef short bf16x8 __attribute__((ext_vector_type(8)));
typedef float f32x4 __attribute__((ext_vector_type(4)));
typedef unsigned short u16x8 __attribute__((ext_vector_type(8)));

#define GLOAD(gp, lp)                                                          \
    __builtin_amdgcn_global_load_lds(                                          \
        (const __attribute__((address_space(1))) void*)(gp),                   \
        (__attribute__((address_space(3))) void*)(lp), 16, 0, 0)

#define PIN8(v)                                                                \
    asm volatile("" ::"v"((v)[0]), "v"((v)[1]), "v"((v)[2]), "v"((v)[3]),      \
                 "v"((v)[4]), "v"((v)[5]), "v"((v)[6]), "v"((v)[7]))
#define PIN2(a, b) asm volatile("" ::"v"(a), "v"(b))

// Problem sizes: B=16, C=256, HW=4096 (64*64)
static constexpr int kB = 16;
static constexpr int kC = 256;
static constexpr int kHW = 4096;

// Workspace layout (float offsets)
static constexpr int OFF_INVC_T = 0;        // 65536 floats
static constexpr int OFF_INVC_S = 65536;    // 65536 floats
static constexpr int OFF_INVD_T = 131072;   // 4096 floats
static constexpr int OFF_INVD_S = 135168;   // 4096 floats
static constexpr int OFF_EXPS   = 139264;   // 16 floats
static constexpr int OFF_POSS   = 139280;   // 16 floats
// bf16 area: teacher raw bf16(x_t) (GEMM B operand), then student: raw bf16,
// overwritten in place by u_s = xb_s*invCs*invCt (GEMM A operand).
static constexpr size_t OFF_U_BYTES = 139296ull * 4ull;
static constexpr size_t U_ELEMS = (size_t)kB * kC * kHW;      // 16777216 per tensor
// psim area after u. Aliased earlier by colnorm partials (64 x 65536 floats
// = 16 MB fp32), consumed by invc_fin_k, then overwritten by gemm partial
// tiles in BF16 (KS*16*65536*2 B = 8 MB at KS=4).
static constexpr size_t OFF_PSIM = 139296ull + 16777216ull;   // float offset

__device__ __forceinline__ unsigned short f2bf(float f) {
    __hip_bfloat16 h = __float2bfloat16(f);
    return __builtin_bit_cast(unsigned short, h);
}
__device__ __forceinline__ float bf2f(unsigned short h) {
    union { unsigned int i; float f; } u;
    u.i = ((unsigned int)h) << 16;
    return u.f;
}

// ---------------- Kernel 1a: fused bf16 cast + colnorm partials --------------
// grid.x = 2048: [ts(2)][b(16)][cslice(32)][hwchunk(2)]. Thread owns 8
// CONTIGUOUS hw; per channel: 2 contiguous f32x4 loads -> FMA into 8
// persistent accumulators -> ONE contiguous 16 B u16x8 store. 8 channels per
// block. Low VGPR (~30) -> 8 blocks/CU; read and write streams both
// full-width contiguous so they can overlap at the coalescer.
__global__ __launch_bounds__(256) void cast_colnorm_k(const float* __restrict__ ten,
                                                      const float* __restrict__ stu,
                                                      float* __restrict__ ws)
{
    int tid = threadIdx.x;
    int t   = blockIdx.x;
    if (t == 0 && tid < 32) ws[OFF_EXPS + tid] = 0.0f;  // zero accumulators

    int hwc = t & 1;
    int cs  = (t >> 1) & 31;
    int b   = (t >> 6) & 15;
    int ts  = t >> 10;                   // 0 = teacher, 1 = student
    const float* src = ts ? stu : ten;

    int hw0 = hwc * 2048 + tid * 8;
    size_t base = (size_t)b * (kC * kHW) + (size_t)cs * 8 * kHW + hw0;
    const float* p = src + base;
    unsigned short* xb = (unsigned short*)((char*)ws + OFF_U_BYTES)
                       + (size_t)ts * U_ELEMS + base;

    f32x4 a0 = {0.0f, 0.0f, 0.0f, 0.0f};
    f32x4 a1 = {0.0f, 0.0f, 0.0f, 0.0f};

#pragma unroll
    for (int ch = 0; ch < 8; ++ch) {
        f32x4 v0 = *(const f32x4*)(p + (size_t)ch * kHW);
        f32x4 v1 = *(const f32x4*)(p + (size_t)ch * kHW + 4);
        PIN2(v0, v1);
        a0[0] += v0[0] * v0[0]; a0[1] += v0[1] * v0[1];
        a0[2] += v0[2] * v0[2]; a0[3] += v0[3] * v0[3];
        a1[0] += v1[0] * v1[0]; a1[1] += v1[1] * v1[1];
        a1[2] += v1[2] * v1[2]; a1[3] += v1[3] * v1[3];
        u16x8 o;
        o[0] = f2bf(v0[0]); o[1] = f2bf(v0[1]); o[2] = f2bf(v0[2]); o[3] = f2bf(v0[3]);
        o[4] = f2bf(v1[0]); o[5] = f2bf(v1[1]); o[6] = f2bf(v1[2]); o[7] = f2bf(v1[3]);
        *(u16x8*)(xb + (size_t)ch * kHW) = o;       // 16 B contiguous store
    }

    // partial[slice = ts*32+cs][b*4096 + hw0], 32 B contiguous per thread
    float* part = ws + OFF_PSIM + ((size_t)(ts * 32 + cs) << 16) + b * kHW + hw0;
    *(f32x4*)part       = a0;
    *(f32x4*)(part + 4) = a1;
}

// ---------------- Kernel 1b: finalize invC (32 slices per tensor) -----------
__global__ __launch_bounds__(256) void invc_fin_k(float* __restrict__ ws)
{
    int g0  = (blockIdx.x * 256 + threadIdx.x) * 4;   // 0..131071
    int ts  = g0 >> 16;
    int pos = g0 & 65535;

    const float* part = ws + OFF_PSIM + ((size_t)(ts * 32) << 16) + pos;
    float4 s = {0.0f, 0.0f, 0.0f, 0.0f};
#pragma unroll
    for (int q = 0; q < 4; ++q) {
        f32x4 v[8];
#pragma unroll
        for (int cs = 0; cs < 8; ++cs)
            v[cs] = *(const f32x4*)(part + ((size_t)(q * 8 + cs) << 16));
        PIN8(v);
#pragma unroll
        for (int cs = 0; cs < 8; ++cs) {
            s.x += v[cs][0]; s.y += v[cs][1]; s.z += v[cs][2]; s.w += v[cs][3];
        }
    }
    float4 o;
    o.x = 1.0f / fmaxf(sqrtf(s.x), 1e-12f);
    o.y = 1.0f / fmaxf(sqrtf(s.y), 1e-12f);
    o.z = 1.0f / fmaxf(sqrtf(s.z), 1e-12f);
    o.w = 1.0f / fmaxf(sqrtf(s.w), 1e-12f);
    *(float4*)(ws + (ts ? OFF_INVC_S : OFF_INVC_T) + pos) = o;
}

// ---------------- Kernel 2: rowscale from bf16 (L3-resident) ----------------
// y=0 teacher: read xb_t, invD_t = 1/||xb_t*invCt||, NO write.
// y=1 student: read xb_s, invD_s = 1/||xb_s*invCs||, write u_s = xb_s*invCs*invCt.
__global__ __launch_bounds__(256) void rowscale_k(float* __restrict__ ws)
{
    int tid = threadIdx.x;
    int bc  = blockIdx.x;               // b*256 + c
    int b   = bc >> 8;
    bool isT = (blockIdx.y == 0);
    unsigned short* u = (unsigned short*)((char*)ws + OFF_U_BYTES)
                      + (isT ? 0 : U_ELEMS) + (size_t)bc * kHW;
    const float* cOwn = ws + (isT ? OFF_INVC_T : OFF_INVC_S) + b * kHW;
    const float* cT   = ws + OFF_INVC_T + b * kHW;
    float* invD       = ws + (isT ? OFF_INVD_T : OFF_INVD_S);

    int e0 = tid * 16;
    u16x8 xa  = *(const u16x8*)(u + e0);
    u16x8 xb2 = *(const u16x8*)(u + e0 + 8);
    f32x4 c[4];
#pragma unroll
    for (int q = 0; q < 4; ++q)
        c[q] = *(const f32x4*)(cOwn + e0 + q * 4);

    float ss = 0.0f;
    if (isT) {
#pragma unroll
        for (int j = 0; j < 8; ++j) {
            float pa = bf2f(xa[j]) * c[j >> 2][j & 3];
            ss += pa * pa;
        }
#pragma unroll
        for (int j = 0; j < 8; ++j) {
            float pb = bf2f(xb2[j]) * c[2 + (j >> 2)][j & 3];
            ss += pb * pb;
        }
    } else {
        f32x4 ct[4];
#pragma unroll
        for (int q = 0; q < 4; ++q)
            ct[q] = *(const f32x4*)(cT + e0 + q * 4);
        u16x8 oa, ob;
#pragma unroll
        for (int j = 0; j < 8; ++j) {
            float pa = bf2f(xa[j]) * c[j >> 2][j & 3];
            ss += pa * pa;
            oa[j] = f2bf(pa * ct[j >> 2][j & 3]);
        }
#pragma unroll
        for (int j = 0; j < 8; ++j) {
            float pb = bf2f(xb2[j]) * c[2 + (j >> 2)][j & 3];
            ss += pb * pb;
            ob[j] = f2bf(pb * ct[2 + (j >> 2)][j & 3]);
        }
        *(u16x8*)(u + e0)     = oa;
        *(u16x8*)(u + e0 + 8) = ob;
    }

#pragma unroll
    for (int o = 32; o; o >>= 1) ss += __shfl_down(ss, o);
    __shared__ float red[4];
    if ((tid & 63) == 0) red[tid >> 6] = ss;
    __syncthreads();
    if (tid == 0)
        invD[bc] = 1.0f / fmaxf(sqrtf(red[0] + red[1] + red[2] + red[3]), 1e-12f);
}

// ---------------- Kernel 3: batched GEMM partials (K-split, bf16 psim) -------
__global__ __launch_bounds__(256) void gemm_part_k(float* __restrict__ ws,
                                                   int kIters)
{
    const unsigned short* uT = (const unsigned short*)((const char*)ws + OFF_U_BYTES);
    const unsigned short* uS = uT + U_ELEMS;

    __shared__ __align__(16) unsigned short As[2][4096];
    __shared__ __align__(16) unsigned short Bs[2][4096];

    int tid = threadIdx.x;
    int bid = blockIdx.x;
    int cpx = gridDim.x >> 3;
    int w   = (bid & 7) * cpx + (bid >> 3);
    int tile = w & 15;
    int g    = w >> 4;
    int b    = g & 15;
    int kz   = g >> 4;
    int tr   = tile >> 2, tc = tile & 3;
    int lane = tid & 63, wid = tid >> 6;
    int wr   = wid >> 1, wc = wid & 1;

    int k0base = kz * (kIters * 64);

    int D0  = tid * 16;
    int r0s = D0 >> 7;
    int c0s = ((D0 & 127) ^ ((r0s & 7) << 4)) >> 1;
    int D1  = 4096 + tid * 16;
    int r1s = D1 >> 7;
    int c1s = ((D1 & 127) ^ ((r1s & 7) << 4)) >> 1;

    const unsigned short* gA = uS + ((size_t)(b * kC + tr * 64) << 12) + k0base;
    const unsigned short* gB = uT + ((size_t)(b * kC + tc * 64) << 12) + k0base;

    f32x4 acc[2][2] = {};

    GLOAD(gA + ((size_t)r0s << 12) + c0s, (char*)As[0] + D0);
    GLOAD(gA + ((size_t)r1s << 12) + c1s, (char*)As[0] + D1);
    GLOAD(gB + ((size_t)r0s << 12) + c0s, (char*)Bs[0] + D0);
    GLOAD(gB + ((size_t)r1s << 12) + c1s, (char*)Bs[0] + D1);
    __syncthreads();

    int cur = 0;
    for (int it = 0; it < kIters; ++it) {
        if (it + 1 < kIters) {
            int k0 = (it + 1) * 64;
            GLOAD(gA + ((size_t)r0s << 12) + k0 + c0s, (char*)As[cur ^ 1] + D0);
            GLOAD(gA + ((size_t)r1s << 12) + k0 + c1s, (char*)As[cur ^ 1] + D1);
            GLOAD(gB + ((size_t)r0s << 12) + k0 + c0s, (char*)Bs[cur ^ 1] + D0);
            GLOAD(gB + ((size_t)r1s << 12) + k0 + c1s, (char*)Bs[cur ^ 1] + D1);
        }
        const char* Ab = (const char*)As[cur];
        const char* Bb = (const char*)Bs[cur];
#pragma unroll
        for (int ks = 0; ks < 2; ++ks) {
            bf16x8 av[2], bv[2];
            int kb = ks * 64 + (lane >> 4) * 16;
#pragma unroll
            for (int f = 0; f < 2; ++f) {
                int row = wr * 32 + f * 16 + (lane & 15);
                av[f] = *(const bf16x8*)(Ab + (row << 7) + (kb ^ ((row & 7) << 4)));
                int col = wc * 32 + f * 16 + (lane & 15);
                bv[f] = *(const bf16x8*)(Bb + (col << 7) + (kb ^ ((col & 7) << 4)));
            }
#pragma unroll
            for (int fr = 0; fr < 2; ++fr)
#pragma unroll
                for (int fc = 0; fc < 2; ++fc)
                    acc[fr][fc] = __builtin_amdgcn_mfma_f32_16x16x32_bf16(
                        av[fr], bv[fc], acc[fr][fc], 0, 0, 0);
        }
        __syncthreads();
        cur ^= 1;
    }

    // bf16 partial tile (|partial| <= ~4 -> err ~1e-3)
    unsigned short* pt = (unsigned short*)(ws + OFF_PSIM)
                       + ((size_t)(kz * 16 + b) << 16);
#pragma unroll
    for (int fr = 0; fr < 2; ++fr)
#pragma unroll
        for (int fc = 0; fc < 2; ++fc) {
            int col = tc * 64 + wc * 32 + fc * 16 + (lane & 15);
#pragma unroll
            for (int j = 0; j < 4; ++j) {
                int row = tr * 64 + wr * 32 + fr * 16 + (lane >> 4) * 4 + j;
                pt[row * 256 + col] = f2bf(acc[fr][fc][j]);
            }
        }
}

// ---------------- Kernel 4: sum bf16 partials + scale + exp/diag reduce -----
__global__ __launch_bounds__(256) void reduce_k(float* __restrict__ ws, int KS)
{
    const unsigned short* psim = (const unsigned short*)(ws + OFF_PSIM);
    const float* invDt = ws + OFF_INVD_T;
    const float* invDs = ws + OFF_INVD_S;

    int b     = blockIdx.x >> 5;                               // 512 blocks
    int local = ((blockIdx.x & 31) << 11) + threadIdx.x * 8;   // 0..65535
    int row   = local >> 8;
    int col   = local & 255;

    float s[8] = {0, 0, 0, 0, 0, 0, 0, 0};
    for (int ks = 0; ks < KS; ++ks) {
        u16x8 v = *(const u16x8*)(psim + (((size_t)(ks * 16 + b)) << 16) + local);
#pragma unroll
        for (int j = 0; j < 8; ++j) s[j] += bf2f(v[j]);
    }
    float  ds  = invDs[b * 256 + row];
    f32x4  dt0 = *(const f32x4*)(invDt + b * 256 + col);
    f32x4  dt1 = *(const f32x4*)(invDt + b * 256 + col + 4);

    float eAcc = 0.0f, pAcc = 0.0f;
#pragma unroll
    for (int j = 0; j < 8; ++j) {
        float dt = (j < 4) ? dt0[j] : dt1[j - 4];
        float v  = s[j] * ds * dt;
        eAcc += __expf(2.0f * v);                              // 1/T = 2
        if (row == col + j) pAcc = v;
    }

#pragma unroll
    for (int o = 32; o; o >>= 1) {
        eAcc += __shfl_down(eAcc, o);
        pAcc += __shfl_down(pAcc, o);
    }
    __shared__ float redE[4], redP[4];
    int lane = threadIdx.x & 63, wid = threadIdx.x >> 6;
    if (lane == 0) { redE[wid] = eAcc; redP[wid] = pAcc; }
    __syncthreads();
    if (threadIdx.x == 0) {
        atomicAdd(ws + OFF_EXPS + b, redE[0] + redE[1] + redE[2] + redE[3]);
        atomicAdd(ws + OFF_POSS + b, redP[0] + redP[1] + redP[2] + redP[3]);
    }
}

// ---------------- Kernel 5: finalize scalar loss -----------------------------
__global__ void finalize_k(const float* __restrict__ ws, float* __restrict__ out)
{
    if (threadIdx.x == 0) {
        const float* expSum = ws + OFF_EXPS;
        const float* posSum = ws + OFF_POSS;
        float loss = 0.0f;
        for (int b = 0; b < kB; ++b)
            loss += -2.0f * posSum[b] / (float)kC + logf(expSum[b]);
        out[0] = loss / (float)kB;
    }
}

extern "C" void kernel_launch(void* const* d_in, const int* in_sizes, int n_in,
                              void* d_out, int out_size, void* d_ws, size_t ws_size,
                              hipStream_t stream)
{
    const float* ten = (const float*)d_in[0];   // teacher_vectors
    const float* stu = (const float*)d_in[1];   // student_vectors
    float* ws  = (float*)d_ws;
    float* out = (float*)d_out;

    int KS = 4;
    {
        size_t base = OFF_PSIM * 4ull;
        if (ws_size < base + 16ull * 1024 * 1024) KS = 2;  // safety
    }
    int kIters = (kHW / KS) / 64;

    cast_colnorm_k<<<dim3(2048), 256, 0, stream>>>(ten, stu, ws);
    invc_fin_k<<<dim3(128), 256, 0, stream>>>(ws);
    rowscale_k<<<dim3(4096, 2), 256, 0, stream>>>(ws);
    gemm_part_k<<<dim3(256 * KS), 256, 0, stream>>>(ws, kIters);
    reduce_k<<<dim3(512), 256, 0, stream>>>(ws, KS);
    finalize_k<<<1, 64, 0, stream>>>(ws, out);
}

// Round 13
// 89.686 us; speedup vs baseline: 1.0346x; 1.0346x over previous
//
#include <hip/hip_runtime.h>
#include <hip/hip_bf16.h>

typedef short bf16x8 __attribute__((ext_vector_type(8)));
typedef float f32x4 __attribute__((ext_vector_type(4)));
typedef unsigned short u16x8 __attribute__((ext_vector_type(8)));

#define GLOAD(gp, lp)                                                          \
    __builtin_amdgcn_global_load_lds(                                          \
        (const __attribute__((address_space(1))) void*)(gp),                   \
        (__attribute__((address_space(3))) void*)(lp), 16, 0, 0)

#define PIN8(v)                                                                \
    asm volatile("" ::"v"((v)[0]), "v"((v)[1]), "v"((v)[2]), "v"((v)[3]),      \
                 "v"((v)[4]), "v"((v)[5]), "v"((v)[6]), "v"((v)[7]))

// Problem sizes: B=16, C=256, HW=4096 (64*64)
static constexpr int kB = 16;
static constexpr int kC = 256;
static constexpr int kHW = 4096;

// Workspace layout (float offsets)
static constexpr int OFF_INVC_T = 0;        // 65536 floats
static constexpr int OFF_INVC_S = 65536;    // 65536 floats
static constexpr int OFF_INVD_T = 131072;   // 4096 floats
static constexpr int OFF_INVD_S = 135168;   // 4096 floats
static constexpr int OFF_EXPS   = 139264;   // 16 floats
static constexpr int OFF_POSS   = 139280;   // 16 floats
// bf16 area: teacher raw bf16(x_t) (GEMM B operand), then student: raw bf16,
// overwritten in place by u_s = xb_s*invCs*invCt (GEMM A operand).
static constexpr size_t OFF_U_BYTES = 139296ull * 4ull;
static constexpr size_t U_ELEMS = (size_t)kB * kC * kHW;      // 16777216 per tensor
// psim area after u. Aliased earlier by colnorm partials (32 x 65536 floats
// = 8 MB fp32), consumed by invc_fin_k, then overwritten by gemm partial
// tiles in BF16 (KS*16*65536*2 B = 8 MB at KS=4).
static constexpr size_t OFF_PSIM = 139296ull + 16777216ull;   // float offset

__device__ __forceinline__ unsigned short f2bf(float f) {
    __hip_bfloat16 h = __float2bfloat16(f);
    return __builtin_bit_cast(unsigned short, h);
}
__device__ __forceinline__ float bf2f(unsigned short h) {
    union { unsigned int i; float f; } u;
    u.i = ((unsigned int)h) << 16;
    return u.f;
}

// ---------------- Kernel 1a: fused bf16 cast + colnorm partials --------------
// Measured-fastest pass-1 shape (r8: 3.8 TB/s combined): thread owns 4 hw,
// 8 channels per pinned batch, strided ushort4 stores. Two batches per block
// (16 channels) so partials shrink to 16 slices/tensor (8 MB total).
// grid.x = 2048: [ts(2)][b(16)][cslice(16)][hwchunk(4)].
__global__ __launch_bounds__(256) void cast_colnorm_k(const float* __restrict__ ten,
                                                      const float* __restrict__ stu,
                                                      float* __restrict__ ws)
{
    int tid = threadIdx.x;
    int t   = blockIdx.x;
    if (t == 0 && tid < 32) ws[OFF_EXPS + tid] = 0.0f;  // zero accumulators

    int hwc = t & 3;
    int cs  = (t >> 2) & 15;
    int b   = (t >> 6) & 15;
    int ts  = t >> 10;                   // 0 = teacher, 1 = student
    const float* src = ts ? stu : ten;

    int hw0 = hwc * 1024 + tid * 4;
    size_t base = (size_t)b * (kC * kHW) + (size_t)cs * 16 * kHW + hw0;
    const float* p = src + base;
    unsigned short* xb = (unsigned short*)((char*)ws + OFF_U_BYTES)
                       + (size_t)ts * U_ELEMS + base;

    f32x4 acc = {0.0f, 0.0f, 0.0f, 0.0f};
#pragma unroll
    for (int g = 0; g < 2; ++g) {
        const float* q = p + (size_t)g * 8 * kHW;
        unsigned short* w = xb + (size_t)g * 8 * kHW;
        f32x4 v[8];
#pragma unroll
        for (int j = 0; j < 8; ++j)
            v[j] = *(const f32x4*)(q + (size_t)j * kHW);
        PIN8(v);
#pragma unroll
        for (int j = 0; j < 8; ++j) {
            acc[0] += v[j][0] * v[j][0];
            acc[1] += v[j][1] * v[j][1];
            acc[2] += v[j][2] * v[j][2];
            acc[3] += v[j][3] * v[j][3];
            ushort4 o;
            o.x = f2bf(v[j][0]); o.y = f2bf(v[j][1]);
            o.z = f2bf(v[j][2]); o.w = f2bf(v[j][3]);
            *(ushort4*)(w + (size_t)j * kHW) = o;
        }
    }

    // partial[slice = ts*16+cs][b*4096 + hw0]
    float* part = ws + OFF_PSIM + ((size_t)(ts * 16 + cs) << 16) + b * kHW + hw0;
    *(f32x4*)part = acc;
}

// ---------------- Kernel 1b: finalize invC (16 slices per tensor) -----------
__global__ __launch_bounds__(256) void invc_fin_k(float* __restrict__ ws)
{
    int g0  = (blockIdx.x * 256 + threadIdx.x) * 4;   // 0..131071
    int ts  = g0 >> 16;
    int pos = g0 & 65535;

    const float* part = ws + OFF_PSIM + ((size_t)(ts * 16) << 16) + pos;
    float4 s = {0.0f, 0.0f, 0.0f, 0.0f};
#pragma unroll
    for (int q = 0; q < 2; ++q) {
        f32x4 v[8];
#pragma unroll
        for (int cs = 0; cs < 8; ++cs)
            v[cs] = *(const f32x4*)(part + ((size_t)(q * 8 + cs) << 16));
        PIN8(v);
#pragma unroll
        for (int cs = 0; cs < 8; ++cs) {
            s.x += v[cs][0]; s.y += v[cs][1]; s.z += v[cs][2]; s.w += v[cs][3];
        }
    }
    float4 o;
    o.x = 1.0f / fmaxf(sqrtf(s.x), 1e-12f);
    o.y = 1.0f / fmaxf(sqrtf(s.y), 1e-12f);
    o.z = 1.0f / fmaxf(sqrtf(s.z), 1e-12f);
    o.w = 1.0f / fmaxf(sqrtf(s.w), 1e-12f);
    *(float4*)(ws + (ts ? OFF_INVC_S : OFF_INVC_T) + pos) = o;
}

// ---------------- Kernel 2: rowscale from bf16 (L3-resident, 8.3 TB/s) ------
// y=0 teacher: read xb_t, invD_t = 1/||xb_t*invCt||, NO write.
// y=1 student: read xb_s, invD_s = 1/||xb_s*invCs||, write u_s = xb_s*invCs*invCt.
__global__ __launch_bounds__(256) void rowscale_k(float* __restrict__ ws)
{
    int tid = threadIdx.x;
    int bc  = blockIdx.x;               // b*256 + c
    int b   = bc >> 8;
    bool isT = (blockIdx.y == 0);
    unsigned short* u = (unsigned short*)((char*)ws + OFF_U_BYTES)
                      + (isT ? 0 : U_ELEMS) + (size_t)bc * kHW;
    const float* cOwn = ws + (isT ? OFF_INVC_T : OFF_INVC_S) + b * kHW;
    const float* cT   = ws + OFF_INVC_T + b * kHW;
    float* invD       = ws + (isT ? OFF_INVD_T : OFF_INVD_S);

    int e0 = tid * 16;
    u16x8 xa  = *(const u16x8*)(u + e0);
    u16x8 xb2 = *(const u16x8*)(u + e0 + 8);
    f32x4 c[4];
#pragma unroll
    for (int q = 0; q < 4; ++q)
        c[q] = *(const f32x4*)(cOwn + e0 + q * 4);

    float ss = 0.0f;
    if (isT) {
#pragma unroll
        for (int j = 0; j < 8; ++j) {
            float pa = bf2f(xa[j]) * c[j >> 2][j & 3];
            ss += pa * pa;
        }
#pragma unroll
        for (int j = 0; j < 8; ++j) {
            float pb = bf2f(xb2[j]) * c[2 + (j >> 2)][j & 3];
            ss += pb * pb;
        }
    } else {
        f32x4 ct[4];
#pragma unroll
        for (int q = 0; q < 4; ++q)
            ct[q] = *(const f32x4*)(cT + e0 + q * 4);
        u16x8 oa, ob;
#pragma unroll
        for (int j = 0; j < 8; ++j) {
            float pa = bf2f(xa[j]) * c[j >> 2][j & 3];
            ss += pa * pa;
            oa[j] = f2bf(pa * ct[j >> 2][j & 3]);
        }
#pragma unroll
        for (int j = 0; j < 8; ++j) {
            float pb = bf2f(xb2[j]) * c[2 + (j >> 2)][j & 3];
            ss += pb * pb;
            ob[j] = f2bf(pb * ct[2 + (j >> 2)][j & 3]);
        }
        *(u16x8*)(u + e0)     = oa;
        *(u16x8*)(u + e0 + 8) = ob;
    }

#pragma unroll
    for (int o = 32; o; o >>= 1) ss += __shfl_down(ss, o);
    __shared__ float red[4];
    if ((tid & 63) == 0) red[tid >> 6] = ss;
    __syncthreads();
    if (tid == 0)
        invD[bc] = 1.0f / fmaxf(sqrtf(red[0] + red[1] + red[2] + red[3]), 1e-12f);
}

// ---------------- Kernel 3: batched GEMM partials (K-split, bf16 psim) -------
__global__ __launch_bounds__(256) void gemm_part_k(float* __restrict__ ws,
                                                   int kIters)
{
    const unsigned short* uT = (const unsigned short*)((const char*)ws + OFF_U_BYTES);
    const unsigned short* uS = uT + U_ELEMS;

    __shared__ __align__(16) unsigned short As[2][4096];
    __shared__ __align__(16) unsigned short Bs[2][4096];

    int tid = threadIdx.x;
    int bid = blockIdx.x;
    int cpx = gridDim.x >> 3;
    int w   = (bid & 7) * cpx + (bid >> 3);
    int tile = w & 15;
    int g    = w >> 4;
    int b    = g & 15;
    int kz   = g >> 4;
    int tr   = tile >> 2, tc = tile & 3;
    int lane = tid & 63, wid = tid >> 6;
    int wr   = wid >> 1, wc = wid & 1;

    int k0base = kz * (kIters * 64);

    int D0  = tid * 16;
    int r0s = D0 >> 7;
    int c0s = ((D0 & 127) ^ ((r0s & 7) << 4)) >> 1;
    int D1  = 4096 + tid * 16;
    int r1s = D1 >> 7;
    int c1s = ((D1 & 127) ^ ((r1s & 7) << 4)) >> 1;

    const unsigned short* gA = uS + ((size_t)(b * kC + tr * 64) << 12) + k0base;
    const unsigned short* gB = uT + ((size_t)(b * kC + tc * 64) << 12) + k0base;

    f32x4 acc[2][2] = {};

    GLOAD(gA + ((size_t)r0s << 12) + c0s, (char*)As[0] + D0);
    GLOAD(gA + ((size_t)r1s << 12) + c1s, (char*)As[0] + D1);
    GLOAD(gB + ((size_t)r0s << 12) + c0s, (char*)Bs[0] + D0);
    GLOAD(gB + ((size_t)r1s << 12) + c1s, (char*)Bs[0] + D1);
    __syncthreads();

    int cur = 0;
    for (int it = 0; it < kIters; ++it) {
        if (it + 1 < kIters) {
            int k0 = (it + 1) * 64;
            GLOAD(gA + ((size_t)r0s << 12) + k0 + c0s, (char*)As[cur ^ 1] + D0);
            GLOAD(gA + ((size_t)r1s << 12) + k0 + c1s, (char*)As[cur ^ 1] + D1);
            GLOAD(gB + ((size_t)r0s << 12) + k0 + c0s, (char*)Bs[cur ^ 1] + D0);
            GLOAD(gB + ((size_t)r1s << 12) + k0 + c1s, (char*)Bs[cur ^ 1] + D1);
        }
        const char* Ab = (const char*)As[cur];
        const char* Bb = (const char*)Bs[cur];
#pragma unroll
        for (int ks = 0; ks < 2; ++ks) {
            bf16x8 av[2], bv[2];
            int kb = ks * 64 + (lane >> 4) * 16;
#pragma unroll
            for (int f = 0; f < 2; ++f) {
                int row = wr * 32 + f * 16 + (lane & 15);
                av[f] = *(const bf16x8*)(Ab + (row << 7) + (kb ^ ((row & 7) << 4)));
                int col = wc * 32 + f * 16 + (lane & 15);
                bv[f] = *(const bf16x8*)(Bb + (col << 7) + (kb ^ ((col & 7) << 4)));
            }
#pragma unroll
            for (int fr = 0; fr < 2; ++fr)
#pragma unroll
                for (int fc = 0; fc < 2; ++fc)
                    acc[fr][fc] = __builtin_amdgcn_mfma_f32_16x16x32_bf16(
                        av[fr], bv[fc], acc[fr][fc], 0, 0, 0);
        }
        __syncthreads();
        cur ^= 1;
    }

    // bf16 partial tile (|partial| <= ~4 -> err ~1e-3)
    unsigned short* pt = (unsigned short*)(ws + OFF_PSIM)
                       + ((size_t)(kz * 16 + b) << 16);
#pragma unroll
    for (int fr = 0; fr < 2; ++fr)
#pragma unroll
        for (int fc = 0; fc < 2; ++fc) {
            int col = tc * 64 + wc * 32 + fc * 16 + (lane & 15);
#pragma unroll
            for (int j = 0; j < 4; ++j) {
                int row = tr * 64 + wr * 32 + fr * 16 + (lane >> 4) * 4 + j;
                pt[row * 256 + col] = f2bf(acc[fr][fc][j]);
            }
        }
}

// ---------------- Kernel 4: sum bf16 partials + scale + exp/diag reduce -----
__global__ __launch_bounds__(256) void reduce_k(float* __restrict__ ws, int KS)
{
    const unsigned short* psim = (const unsigned short*)(ws + OFF_PSIM);
    const float* invDt = ws + OFF_INVD_T;
    const float* invDs = ws + OFF_INVD_S;

    int b     = blockIdx.x >> 5;                               // 512 blocks
    int local = ((blockIdx.x & 31) << 11) + threadIdx.x * 8;   // 0..65535
    int row   = local >> 8;
    int col   = local & 255;

    float s[8] = {0, 0, 0, 0, 0, 0, 0, 0};
    for (int ks = 0; ks < KS; ++ks) {
        u16x8 v = *(const u16x8*)(psim + (((size_t)(ks * 16 + b)) << 16) + local);
#pragma unroll
        for (int j = 0; j < 8; ++j) s[j] += bf2f(v[j]);
    }
    float  ds  = invDs[b * 256 + row];
    f32x4  dt0 = *(const f32x4*)(invDt + b * 256 + col);
    f32x4  dt1 = *(const f32x4*)(invDt + b * 256 + col + 4);

    float eAcc = 0.0f, pAcc = 0.0f;
#pragma unroll
    for (int j = 0; j < 8; ++j) {
        float dt = (j < 4) ? dt0[j] : dt1[j - 4];
        float v  = s[j] * ds * dt;
        eAcc += __expf(2.0f * v);                              // 1/T = 2
        if (row == col + j) pAcc = v;
    }

#pragma unroll
    for (int o = 32; o; o >>= 1) {
        eAcc += __shfl_down(eAcc, o);
        pAcc += __shfl_down(pAcc, o);
    }
    __shared__ float redE[4], redP[4];
    int lane = threadIdx.x & 63, wid = threadIdx.x >> 6;
    if (lane == 0) { redE[wid] = eAcc; redP[wid] = pAcc; }
    __syncthreads();
    if (threadIdx.x == 0) {
        atomicAdd(ws + OFF_EXPS + b, redE[0] + redE[1] + redE[2] + redE[3]);
        atomicAdd(ws + OFF_POSS + b, redP[0] + redP[1] + redP[2] + redP[3]);
    }
}

// ---------------- Kernel 5: finalize scalar loss -----------------------------
__global__ void finalize_k(const float* __restrict__ ws, float* __restrict__ out)
{
    if (threadIdx.x == 0) {
        const float* expSum = ws + OFF_EXPS;
        const float* posSum = ws + OFF_POSS;
        float loss = 0.0f;
        for (int b = 0; b < kB; ++b)
            loss += -2.0f * posSum[b] / (float)kC + logf(expSum[b]);
        out[0] = loss / (float)kB;
    }
}

extern "C" void kernel_launch(void* const* d_in, const int* in_sizes, int n_in,
                              void* d_out, int out_size, void* d_ws, size_t ws_size,
                              hipStream_t stream)
{
    const float* ten = (const float*)d_in[0];   // teacher_vectors
    const float* stu = (const float*)d_in[1];   // student_vectors
    float* ws  = (float*)d_ws;
    float* out = (float*)d_out;

    int KS = 4;
    {
        size_t base = OFF_PSIM * 4ull;
        if (ws_size < base + 16ull * 1024 * 1024) KS = 2;  // safety
    }
    int kIters = (kHW / KS) / 64;

    cast_colnorm_k<<<dim3(2048), 256, 0, stream>>>(ten, stu, ws);
    invc_fin_k<<<dim3(128), 256, 0, stream>>>(ws);
    rowscale_k<<<dim3(4096, 2), 256, 0, stream>>>(ws);
    gemm_part_k<<<dim3(256 * KS), 256, 0, stream>>>(ws, kIters);
    reduce_k<<<dim3(512), 256, 0, stream>>>(ws, KS);
    finalize_k<<<1, 64, 0, stream>>>(ws, out);
}